// Round 2
// baseline (222.211 us; speedup 1.0000x reference)
//
#include <hip/hip_runtime.h>

// ConvSoftArgmax2d: x (8,16,512,512) fp32 -> coords (128,2,256,256), resp (128,1,256,256)
// 3x3 window, stride 2, pad 1. Padding contributes 0 to the pooled exp-sums.
// v2.1: 2 outputs/thread (one aligned float4 + shfl_up per row), XCD-chunked
//       block swizzle for shared-row L2 locality, nontemporal output stores
//       (native ext_vector_type for the builtin — HIP float2 is rejected).

#define H  512
#define W  512
#define HO 256
#define WO 256
#define BC 128

typedef float v2f __attribute__((ext_vector_type(2)));

__global__ __launch_bounds__(256) void casm_kernel(
    const float* __restrict__ x, const float* __restrict__ temp,
    float* __restrict__ out)
{
    // XCD-chunked swizzle: nblk = 16384 (divisible by 8). Keeps ho-adjacent
    // blocks (which share one input row) on the same XCD's L2.
    int nblk = gridDim.x;
    int bid  = blockIdx.x;
    int swz  = (bid & 7) * (nblk >> 3) + (bid >> 3);

    int idx = swz * 256 + (int)threadIdx.x;
    int t   = idx & 127;              // pair index: wo = 2t, 2t+1 (128 thr/row)
    int ho  = (idx >> 7) & (HO - 1);  // wave-uniform
    int bc  = idx >> 15;

    // exp(v/T) = exp2(v * log2e / T)
    float k = 1.44269504088896340736f / fmaxf(temp[0], 1e-8f);

    const float* __restrict__ xp = x + (size_t)bc * (H * W);
    int r0 = 2 * ho - 1;              // only ho==0 gives r0 < 0 (wave-uniform)
    int cM = 4 * t;                   // 16B-aligned float4 column base
    float mL = (t == 0) ? 0.0f : 1.0f; // left-column pad mask (wo==0)

    // window a: cols 4t-1, 4t, 4t+1   window b: cols 4t+1, 4t+2, 4t+3
    float den_a = 0.f, den_b = 0.f, cyn_a = 0.f, cyn_b = 0.f;
    float colL_a = 0.f, colR_a = 0.f, colL_b = 0.f, colR_b = 0.f;
    float num_a = 0.f, num_b = 0.f;

#pragma unroll
    for (int rr = 0; rr < 3; ++rr) {
        if (rr == 0 && r0 < 0) continue;          // wave-uniform branch
        const float* __restrict__ row = xp + (r0 + rr) * W;
        float4 v = *(const float4*)(row + cM);
        float vL = __shfl_up(v.w, 1);             // lane-1's col 4t-1
        if ((t & 63) == 0 && t != 0) vL = row[cM - 1];  // wave-boundary lane
        float eL = mL * __builtin_amdgcn_exp2f(k * vL);
        float e0 = __builtin_amdgcn_exp2f(k * v.x);
        float e1 = __builtin_amdgcn_exp2f(k * v.y);
        float e2 = __builtin_amdgcn_exp2f(k * v.z);
        float e3 = __builtin_amdgcn_exp2f(k * v.w);
        float rs_a = eL + e0 + e1;
        float rs_b = e1 + e2 + e3;
        den_a += rs_a;  den_b += rs_b;
        if (rr == 0) { cyn_a -= rs_a; cyn_b -= rs_b; }   // cy num = s2 - s0
        if (rr == 2) { cyn_a += rs_a; cyn_b += rs_b; }
        colL_a += eL;  colR_a += e1;
        colL_b += e1;  colR_b += e3;
        num_a = fmaf(eL, vL, fmaf(e0, v.x, fmaf(e1, v.y, num_a)));
        num_b = fmaf(e1, v.y, fmaf(e2, v.z, fmaf(e3, v.w, num_b)));
    }

    float ia = __builtin_amdgcn_rcpf(den_a + 1e-12f);
    float ib = __builtin_amdgcn_rcpf(den_b + 1e-12f);
    const float scale = 2.0f / 511.0f;
    int wo0 = 2 * t;
    v2f vx = { ((colR_a - colL_a) * ia + (float)(2 * wo0    )) * scale - 1.0f,
               ((colR_b - colL_b) * ib + (float)(2 * wo0 + 2)) * scale - 1.0f };
    v2f vy = { (cyn_a * ia + (float)(2 * ho)) * scale - 1.0f,
               (cyn_b * ib + (float)(2 * ho)) * scale - 1.0f };
    v2f vr = { num_a * ia, num_b * ib };

    size_t pix   = (size_t)ho * WO + wo0;                 // even -> 8B aligned
    size_t cbase = (size_t)bc * (2 * HO * WO) + pix;
    __builtin_nontemporal_store(vx, (v2f*)(out + cbase));                    // ch0: x
    __builtin_nontemporal_store(vy, (v2f*)(out + cbase + HO * WO));          // ch1: y
    __builtin_nontemporal_store(vr, (v2f*)(out + (size_t)BC * 2 * HO * WO
                                           + (size_t)bc * HO * WO + pix));   // resp
}

extern "C" void kernel_launch(void* const* d_in, const int* in_sizes, int n_in,
                              void* d_out, int out_size, void* d_ws, size_t ws_size,
                              hipStream_t stream) {
    const float* x    = (const float*)d_in[0];
    const float* temp = (const float*)d_in[1];
    float* out        = (float*)d_out;

    int total  = BC * HO * (WO / 2);    // 4,194,304 threads, 2 outputs each
    int blocks = total / 256;           // 16384
    casm_kernel<<<blocks, 256, 0, stream>>>(x, temp, out);
}